// Round 4
// baseline (430.787 us; speedup 1.0000x reference)
//
#include <hip/hip_runtime.h>
#include <math.h>

#define T_TOK 8192
#define D_DIM 2048
#define E_EXP 64
#define CAP   256
#define CHUNK 64            // tokens per gate/rank block
#define NCHUNK 128          // T_TOK / CHUNK
#define TEC   (134217728LL) // T*E*C
#define TE    (T_TOK * E_EXP)
#define KSPLIT 4
#define ROWBLK 64
#define N_GEMM_BLK 512      // (T/ROWBLK) * KSPLIT
#define N_FILL_BLK 2048

typedef float f32x4 __attribute__((ext_vector_type(4)));

// ---------------- K_A: fused output zero-fill + split-K logits GEMM ----------------
// blocks [0,512): GEMM partial tile (64 rows x 64 experts, K-chunk of 512).
// blocks [512, 2560): zero-fill 131072 floats each of d_out (nontemporal).
__global__ __launch_bounds__(256) void k_fill_gemm(const float* __restrict__ x,
                                                   const float* __restrict__ wg,
                                                   float* __restrict__ part,
                                                   float* __restrict__ dout) {
  const int tid = threadIdx.x;
  if (blockIdx.x >= N_GEMM_BLK) {
    // ---- fill role ----
    const long long cb = blockIdx.x - N_GEMM_BLK;  // 0..2047
    const f32x4 z = (f32x4)(0.f);
    f32x4* base = reinterpret_cast<f32x4*>(dout) + cb * 32768 + tid;
#pragma unroll 4
    for (int i = 0; i < 128; ++i) __builtin_nontemporal_store(z, base + i * 256);
    if (cb == 0 && tid == 0) dout[2LL * TEC] = 0.f;  // last element (odd tail)
    return;
  }
  // ---- GEMM role: rows [row0,row0+64), K in [kc*512, kc*512+512) ----
  __shared__ float xs[ROWBLK * 64];
  __shared__ float es[E_EXP * 64];
  const int gb = blockIdx.x;
  const int rowblk = gb >> 2;
  const int kc = gb & 3;
  const int row0 = rowblk * ROWBLK;
  const int kbase = kc * 512;
  const int r = tid >> 2;   // 0..63 (staging row)
  const int q = tid & 3;    // granule quarter
  const float* xrow = x + (size_t)(row0 + r) * D_DIM + kbase;
  const float* erow = wg + (size_t)r * D_DIM + kbase;
  float4 ax[4], bx[4];

#define ISSUE(t)                                                              \
  {                                                                           \
    const int kk = (t) * 64;                                                  \
    _Pragma("unroll") for (int i = 0; i < 4; ++i) {                           \
      ax[i] = *reinterpret_cast<const float4*>(xrow + kk + (q + 4 * i) * 4);  \
      bx[i] = *reinterpret_cast<const float4*>(erow + kk + (q + 4 * i) * 4);  \
    }                                                                         \
  }
#define WRITE()                                                               \
  {                                                                           \
    _Pragma("unroll") for (int i = 0; i < 4; ++i) {                           \
      const int gi = q + 4 * i;                                               \
      const int pos = gi ^ (r & 7);                                           \
      *reinterpret_cast<float4*>(&xs[(r * 16 + pos) * 4]) = ax[i];            \
      *reinterpret_cast<float4*>(&es[(r * 16 + pos) * 4]) = bx[i];            \
    }                                                                         \
  }

  float acc[4][4] = {{0.f}};
  const int tr = tid & 15;   // output rows tr+16j
  const int tc = tid >> 4;   // output cols tc+16j
  ISSUE(0);
  WRITE();
  __syncthreads();
  for (int t = 0; t < 8; ++t) {
    if (t < 7) ISSUE(t + 1);
#pragma unroll
    for (int g = 0; g < 16; ++g) {
      float4 a[4], b[4];
#pragma unroll
      for (int j = 0; j < 4; ++j) {
        const int ra = tr + 16 * j;
        const int rb = tc + 16 * j;
        a[j] = *reinterpret_cast<const float4*>(&xs[(ra * 16 + (g ^ (ra & 7))) * 4]);
        b[j] = *reinterpret_cast<const float4*>(&es[(rb * 16 + (g ^ (rb & 7))) * 4]);
      }
#pragma unroll
      for (int jr = 0; jr < 4; ++jr)
#pragma unroll
        for (int jc = 0; jc < 4; ++jc) {
          acc[jr][jc] = fmaf(a[jr].x, b[jc].x, acc[jr][jc]);
          acc[jr][jc] = fmaf(a[jr].y, b[jc].y, acc[jr][jc]);
          acc[jr][jc] = fmaf(a[jr].z, b[jc].z, acc[jr][jc]);
          acc[jr][jc] = fmaf(a[jr].w, b[jc].w, acc[jr][jc]);
        }
    }
    __syncthreads();
    if (t < 7) {
      WRITE();
      __syncthreads();
    }
  }
  float* pbase = part + (size_t)kc * TE;
#pragma unroll
  for (int jr = 0; jr < 4; ++jr)
#pragma unroll
    for (int jc = 0; jc < 4; ++jc)
      pbase[(size_t)(row0 + tr + 16 * jr) * E_EXP + tc + 16 * jc] = acc[jr][jc];
#undef ISSUE
#undef WRITE
}

// ---------------- K_B: fused gate (softmax+top1+top2) + local rank + hist ----------------
// 128 blocks x 128 threads (2 waves); block handles CHUNK=64 tokens.
// Reduces the 4 split-K partials in fixed order -> deterministic logits.
__global__ __launch_bounds__(128) void k_gate_rank(const float* __restrict__ part,
                                                   const float* __restrict__ gumbel,
                                                   float* __restrict__ colpart,
                                                   int* __restrict__ idx1g,
                                                   int* __restrict__ idx2g,
                                                   float* __restrict__ g1v,
                                                   float* __restrict__ g2v,
                                                   int* __restrict__ rank1,
                                                   int* __restrict__ rank2,
                                                   int* __restrict__ hist1,
                                                   int* __restrict__ hist2) {
  const int lane = threadIdx.x & 63;
  const int wave = threadIdx.x >> 6;
  const int base = blockIdx.x * CHUNK;
  __shared__ int sIdx1[CHUNK], sIdx2[CHUNK];
  __shared__ float cs[2][64];
  __shared__ int h1[64], h2[64];
  if (threadIdx.x < 64) { h1[threadIdx.x] = 0; h2[threadIdx.x] = 0; }
  float colacc = 0.f;
  for (int i = 0; i < 32; ++i) {
    const int lt = wave * 32 + i;
    const int t = base + lt;
    const int o = t * 64 + lane;
    const float L = ((part[o] + part[TE + o]) + (part[2 * TE + o] + part[3 * TE + o]));
    float m = L;
#pragma unroll
    for (int off = 32; off; off >>= 1) m = fmaxf(m, __shfl_xor(m, off));
    const float e = expf(L - m);
    float s = e;
#pragma unroll
    for (int off = 32; off; off >>= 1) s += __shfl_xor(s, off);
    const float g = e / s;
    colacc += g;
    // argmax1 over gates, first-max (ties -> lowest index)
    float v = g; int ix = lane;
#pragma unroll
    for (int off = 32; off; off >>= 1) {
      const float v2 = __shfl_xor(v, off); const int i2 = __shfl_xor(ix, off);
      if (v2 > v || (v2 == v && i2 < ix)) { v = v2; ix = i2; }
    }
    const int i1 = ix;
    const float gate1 = __shfl(g, i1);
    // argmax2 over noised logits, expert i1 masked
    float nz = L + gumbel[o];
    if (lane == i1) nz = -INFINITY;
    float vv = nz; int jx = lane;
#pragma unroll
    for (int off = 32; off; off >>= 1) {
      const float v2 = __shfl_xor(vv, off); const int j2 = __shfl_xor(jx, off);
      if (v2 > vv || (v2 == vv && j2 < jx)) { vv = v2; jx = j2; }
    }
    const int i2x = jx;
    const float gate2 = __shfl(g, i2x);
    if (lane == 0) {
      sIdx1[lt] = i1; sIdx2[lt] = i2x;
      idx1g[t] = i1; idx2g[t] = i2x;
      g1v[t] = gate1; g2v[t] = gate2;
    }
  }
  cs[wave][lane] = colacc;
  __syncthreads();
  if (wave == 0) colpart[blockIdx.x * 64 + lane] = cs[0][lane] + cs[1][lane];
  const int tid = threadIdx.x;
  if (tid < CHUNK) {
    const int my1 = sIdx1[tid], my2 = sIdx2[tid];
    int r1 = 0, r2 = 0;
    for (int j = 0; j < CHUNK; ++j) {
      r1 += (j < tid && sIdx1[j] == my1);
      r2 += (j < tid && sIdx2[j] == my2);
    }
    atomicAdd(&h1[my1], 1);
    atomicAdd(&h2[my2], 1);
    rank1[base + tid] = r1;
    rank2[base + tid] = r2;
  }
  __syncthreads();
  if (tid < 64) {
    hist1[blockIdx.x * 64 + tid] = h1[tid];
    hist2[blockIdx.x * 64 + tid] = h2[tid];
  }
}

// ---------------- K_C: chunk-prefix offsets + l_aux ----------------
__global__ __launch_bounds__(64) void k_prefix(const int* __restrict__ hist1,
                                               const int* __restrict__ hist2,
                                               const float* __restrict__ colpart,
                                               int* __restrict__ offs1,
                                               int* __restrict__ offs2,
                                               float* __restrict__ dout) {
  const int e = threadIdx.x;
  int run = 0;
  for (int c = 0; c < NCHUNK; ++c) { offs1[c * 64 + e] = run; run += hist1[c * 64 + e]; }
  const int total1 = run;
  int run2 = total1;  // locations2 includes sum(mask1, axis=0)
  for (int c = 0; c < NCHUNK; ++c) { offs2[c * 64 + e] = run2; run2 += hist2[c * 64 + e]; }
  float csum = 0.f;
  for (int b = 0; b < NCHUNK; ++b) csum += colpart[b * 64 + e];
  const float me = csum / (float)T_TOK;
  const float ce = (float)total1 / (float)T_TOK;
  float val = me * ce;
#pragma unroll
  for (int o = 32; o; o >>= 1) val += __shfl_xor(val, o);
  if (e == 0) dout[0] = val * (float)E_EXP;  // mean(me*ce)*E*E = sum*E
}

// ---------------- K_D: sparse patch of combine weights + dispatch ----------------
__global__ __launch_bounds__(256) void k_scatter(const int* __restrict__ idx1g,
                                                 const int* __restrict__ idx2g,
                                                 const float* __restrict__ g1v,
                                                 const float* __restrict__ g2v,
                                                 const int* __restrict__ rank1,
                                                 const int* __restrict__ rank2,
                                                 const int* __restrict__ offs1,
                                                 const int* __restrict__ offs2,
                                                 float* __restrict__ dout) {
  const int t = blockIdx.x * 256 + threadIdx.x;
  const int c = t >> 6;  // CHUNK=64
  const int e1 = idx1g[t], e2 = idx2g[t];
  const int loc1 = offs1[c * 64 + e1] + rank1[t];
  const int loc2 = offs2[c * 64 + e2] + rank2[t];
  const bool k1 = loc1 < CAP;
  const bool k2 = loc2 < CAP;
  const float a = k1 ? g1v[t] : 0.f;
  const float b = k2 ? g2v[t] : 0.f;
  const float denom = fmaxf(a + b, 1.1920929e-7f);  // FLT_EPSILON
  if (k1) {
    const long long o = 1LL + ((long long)t * 64 + e1) * 256 + loc1;
    dout[o] = a / denom;
    dout[o + TEC] = 1.0f;
  }
  if (k2) {
    const long long o = 1LL + ((long long)t * 64 + e2) * 256 + loc2;
    dout[o] = b / denom;
    dout[o + TEC] = 1.0f;
  }
}

extern "C" void kernel_launch(void* const* d_in, const int* in_sizes, int n_in,
                              void* d_out, int out_size, void* d_ws, size_t ws_size,
                              hipStream_t stream) {
  const float* x = (const float*)d_in[0];
  const float* wg = (const float*)d_in[1];
  const float* gumbel = (const float*)d_in[2];
  float* dout = (float*)d_out;

  char* p = (char*)d_ws;
  float* part = (float*)p;     p += (size_t)KSPLIT * TE * 4;  // 8 MB split-K partials
  float* colpart = (float*)p;  p += NCHUNK * 64 * 4;
  float* g1v = (float*)p;      p += T_TOK * 4;
  float* g2v = (float*)p;      p += T_TOK * 4;
  int* idx1g = (int*)p;        p += T_TOK * 4;
  int* idx2g = (int*)p;        p += T_TOK * 4;
  int* rank1 = (int*)p;        p += T_TOK * 4;
  int* rank2 = (int*)p;        p += T_TOK * 4;
  int* hist1 = (int*)p;        p += NCHUNK * 64 * 4;
  int* hist2 = (int*)p;        p += NCHUNK * 64 * 4;
  int* offs1 = (int*)p;        p += NCHUNK * 64 * 4;
  int* offs2 = (int*)p;        p += NCHUNK * 64 * 4;

  k_fill_gemm<<<N_GEMM_BLK + N_FILL_BLK, 256, 0, stream>>>(x, wg, part, dout);
  k_gate_rank<<<NCHUNK, 128, 0, stream>>>(part, gumbel, colpart, idx1g, idx2g,
                                          g1v, g2v, rank1, rank2, hist1, hist2);
  k_prefix<<<1, 64, 0, stream>>>(hist1, hist2, colpart, offs1, offs2, dout);
  k_scatter<<<T_TOK / 256, 256, 0, stream>>>(idx1g, idx2g, g1v, g2v, rank1, rank2,
                                             offs1, offs2, dout);
}